// Round 7
// baseline (46.484 us; speedup 1.0000x reference)
//
#include <hip/hip_runtime.h>
#include <hip/hip_bf16.h>
#include <math.h>

typedef __attribute__((ext_vector_type(8))) short short8;
typedef __attribute__((ext_vector_type(4))) float f32x4;

#define N 8192
#define D 256
#define INV_T 10.0f
#define EPSN 1e-8f

__device__ __forceinline__ unsigned short f2bf(float x) {
  unsigned int u = __float_as_uint(x);
  u += 0x7fffu + ((u >> 16) & 1u);
  return (unsigned short)(u >> 16);
}

__device__ __forceinline__ void async16(void* lds, const void* g) {
  __builtin_amdgcn_global_load_lds(
      (const __attribute__((address_space(1))) void*)g,
      (__attribute__((address_space(3))) void*)lds,
      16, 0, 0);
}

// Sum over each 16-lane group via DPP row_shr adds (VALU pipe, no DS traffic).
// Result valid in lane 15 of each group.
__device__ __forceinline__ float rowsum16(float v) {
  v += __uint_as_float(__builtin_amdgcn_update_dpp(
      0u, __float_as_uint(v), 0x118, 0xf, 0xf, true));  // row_shr:8
  v += __uint_as_float(__builtin_amdgcn_update_dpp(
      0u, __float_as_uint(v), 0x114, 0xf, 0xf, true));  // row_shr:4
  v += __uint_as_float(__builtin_amdgcn_update_dpp(
      0u, __float_as_uint(v), 0x112, 0xf, 0xf, true));  // row_shr:2
  v += __uint_as_float(__builtin_amdgcn_update_dpp(
      0u, __float_as_uint(v), 0x111, 0xf, 0xf, true));  // row_shr:1
  return v;
}

// One wave per row: fp32 norm, bf16 normalized row. Also zeroes rowsum + out.
__global__ __launch_bounds__(256) void normalize_k(const float* __restrict__ feats,
                                                   unsigned short* __restrict__ fn,
                                                   float* __restrict__ rowsum,
                                                   float* __restrict__ out) {
  int row = blockIdx.x * 4 + (threadIdx.x >> 6);
  int lane = threadIdx.x & 63;
  if (threadIdx.x < 4) rowsum[blockIdx.x * 4 + threadIdx.x] = 0.0f;
  if (blockIdx.x == 0 && threadIdx.x == 0) out[0] = 0.0f;
  float4 v = ((const float4*)(feats + (size_t)row * D))[lane];
  float ss = v.x * v.x + v.y * v.y + v.z * v.z + v.w * v.w;
#pragma unroll
  for (int off = 32; off; off >>= 1) ss += __shfl_xor(ss, off, 64);
  float inv = 1.0f / fmaxf(sqrtf(ss), EPSN);
  uint2 o;
  o.x = (unsigned)f2bf(v.x * inv) | ((unsigned)f2bf(v.y * inv) << 16);
  o.y = (unsigned)f2bf(v.z * inv) | ((unsigned)f2bf(v.w * inv) << 16);
  ((uint2*)(fn + (size_t)row * D))[lane] = o;
}

// Fused symmetric GEMM (C = fn*fn^T/T) + exp(C-10) row/col-sum + pos harvest.
// 128x128 tile, triangular blocks (bm<=bn), BK=64, 4 waves (2x2), each wave
// owns 64x64 (4x4 16x16x32 frags -> 32 FLOP per LDS byte, 1.5x the 64x32
// wave tile). LDS XOR-swizzled both-sides; counted-vmcnt pipeline (next tile
// stays in flight across the barrier). Row-reduce via DPP (VALU pipe).
__global__ __launch_bounds__(256) void gemm_lse(const unsigned short* __restrict__ fn,
                                                float* __restrict__ rowsum,
                                                float* __restrict__ pos) {
  __shared__ unsigned short As[2][128 * 64];
  __shared__ unsigned short Bs[2][128 * 64];
  __shared__ float lrow[128];
  __shared__ float lcol[128];
  int tid = threadIdx.x;
  int wave = tid >> 6, lane = tid & 63;
  int wm = wave >> 1, wn = wave & 1;
  int hi = lane >> 4, lo = lane & 15;

  // XCD-chunked triangular order: 2080 = 8 * 260, bijective.
  int b = blockIdx.x;
  int t = (b & 7) * 260 + (b >> 3);
  int bm = (int)((129.0 - sqrt((double)(16641 - 8 * t))) * 0.5);
  int S = bm * (129 - bm) / 2;
  if (t < S) { --bm; S = bm * (129 - bm) / 2; }
  else { int S1 = (bm + 1) * (128 - bm) / 2; if (t >= S1) { ++bm; S = S1; } }
  int bn = bm + (t - S);

  const char* fb = (const char*)fn;

  auto stage = [&](int buf, int kt) {
    int k0b = kt * 128;  // byte offset along K (BK*2)
#pragma unroll
    for (int inst = 0; inst < 4; ++inst) {
      int o = tid * 16 + inst * 4096;      // linear LDS byte offset
      int r = o >> 7;                      // tile row
      int cs = (o & 127) ^ ((r & 7) << 4); // pre-swizzled source column byte
      const char* ga = fb + (size_t)(bm * 128 + r) * (D * 2) + k0b + cs;
      const char* gb = fb + (size_t)(bn * 128 + r) * (D * 2) + k0b + cs;
      async16((char*)&As[buf][0] + o, ga);
      async16((char*)&Bs[buf][0] + o, gb);
    }
  };

  f32x4 acc[4][4];
#pragma unroll
  for (int m = 0; m < 4; ++m)
#pragma unroll
    for (int n = 0; n < 4; ++n) acc[m][n] = (f32x4){0.f, 0.f, 0.f, 0.f};

  auto compute = [&](int buf) {
#pragma unroll
    for (int ks = 0; ks < 2; ++ks) {
      int cbyte = ks * 64 + hi * 16;  // 16B-aligned column byte
      short8 af[4], bfr[4];
#pragma unroll
      for (int m = 0; m < 4; ++m) {
        int R = wm * 64 + m * 16 + lo;
        af[m] = *(const short8*)((const char*)&As[buf][0] + R * 128 +
                                 (cbyte ^ ((R & 7) << 4)));
      }
#pragma unroll
      for (int n = 0; n < 4; ++n) {
        int R = wn * 64 + n * 16 + lo;
        bfr[n] = *(const short8*)((const char*)&Bs[buf][0] + R * 128 +
                                  (cbyte ^ ((R & 7) << 4)));
      }
#pragma unroll
      for (int m = 0; m < 4; ++m)
#pragma unroll
        for (int n = 0; n < 4; ++n)
          acc[m][n] = __builtin_amdgcn_mfma_f32_16x16x32_bf16(af[m], bfr[n],
                                                              acc[m][n], 0, 0, 0);
    }
  };

  stage(0, 0);          // 8 loads/thread
  stage(1, 1);          // 8 more: 16 outstanding
  if (tid < 128) { lrow[tid] = 0.0f; lcol[tid] = 0.0f; }

#pragma unroll
  for (int kt = 0; kt < 4; ++kt) {
    if (kt < 3) asm volatile("s_waitcnt vmcnt(8)" ::: "memory");
    else        asm volatile("s_waitcnt vmcnt(0)" ::: "memory");
    __builtin_amdgcn_s_barrier();        // all waves' tile-kt loads landed
    __builtin_amdgcn_sched_barrier(0);   // pin ds_reads below the barrier
    compute(kt & 1);
    asm volatile("s_waitcnt lgkmcnt(0)" ::: "memory");  // own ds_reads done
    __builtin_amdgcn_sched_barrier(0);
    __builtin_amdgcn_s_barrier();        // WAR: everyone done reading buf
    if (kt < 2) stage(kt & 1, kt + 2);   // refill the buffer just consumed
  }

  // Epilogue. C frag layout: col = lane&15, row = (lane>>4)*4 + reg.
  bool isdiag = (bm == bn);
  float ca[4] = {0.f, 0.f, 0.f, 0.f};
  int rbase = wm * 64, cbase = wn * 64;
#pragma unroll
  for (int m = 0; m < 4; ++m) {
#pragma unroll
    for (int j = 0; j < 4; ++j) {
      int rloc = rbase + m * 16 + hi * 4 + j;
      float v = 0.f;
#pragma unroll
      for (int n = 0; n < 4; ++n) {
        float e = __expf(fmaf(acc[m][n][j], 10.0f, -10.0f));
        if (isdiag && rloc == cbase + n * 16 + lo) e = 0.f;
        v += e;
        ca[n] += e;
      }
      v = rowsum16(v);  // DPP: VALU pipe, no DS traffic
      if (lo == 15) atomicAdd(&lrow[rloc], v);
    }
  }
  if (!isdiag) {
#pragma unroll
    for (int n = 0; n < 4; ++n) {
      float c = ca[n];
      c += __shfl_xor(c, 16, 64);
      c += __shfl_xor(c, 32, 64);
      if (hi == 0) atomicAdd(&lcol[cbase + n * 16 + lo], c);
    }
  }
  // pos harvest: block (bm, bm+32) local diagonal = sim[i, i+4096].
  if (bn == bm + 32) {
#pragma unroll
    for (int m = 0; m < 4; ++m) {
      int rb = wm * 64 + m * 16;
#pragma unroll
      for (int n = 0; n < 4; ++n) {
        if (rb == wn * 64 + n * 16 && (lo >> 2) == hi) {
          int j = lo & 3;
          f32x4 a = acc[m][n];
          float pv = (j == 0) ? a[0] : (j == 1) ? a[1] : (j == 2) ? a[2] : a[3];
          pv *= INV_T;
          int gr = bm * 128 + rb + lo;
          pos[gr] = pv;
          pos[gr + N / 2] = pv;
        }
      }
    }
  }
  __syncthreads();
  if (tid < 128) {
    atomicAdd(&rowsum[bm * 128 + tid], lrow[tid]);
    if (!isdiag) atomicAdd(&rowsum[bn * 128 + tid], lcol[tid]);
  }
}

// 32 blocks x 256 threads: one row each, partial-reduce, atomic accumulate.
__global__ __launch_bounds__(256) void final_k(const float* __restrict__ rowsum,
                                               const float* __restrict__ pos,
                                               float* __restrict__ out) {
  int tid = threadIdx.x;
  int i = blockIdx.x * 256 + tid;
  float s = 10.0f + logf(rowsum[i]) - pos[i];
#pragma unroll
  for (int off = 32; off; off >>= 1) s += __shfl_xor(s, off, 64);
  __shared__ float red[4];
  if ((tid & 63) == 0) red[tid >> 6] = s;
  __syncthreads();
  if (tid == 0)
    atomicAdd(out, (red[0] + red[1] + red[2] + red[3]) * (1.0f / N));
}

extern "C" void kernel_launch(void* const* d_in, const int* in_sizes, int n_in,
                              void* d_out, int out_size, void* d_ws, size_t ws_size,
                              hipStream_t stream) {
  const float* feats = (const float*)d_in[0];
  float* out = (float*)d_out;
  char* ws = (char*)d_ws;
  unsigned short* fn = (unsigned short*)ws;                    // 4 MB bf16 normalized feats
  float* pos = (float*)(ws + 4 * 1024 * 1024);                 // 32 KB
  float* rowsum = (float*)(ws + 4 * 1024 * 1024 + 32 * 1024);  // 32 KB

  normalize_k<<<N / 4, 256, 0, stream>>>(feats, fn, rowsum, out);
  gemm_lse<<<(64 * 65) / 2, 256, 0, stream>>>(fn, rowsum, pos);
  final_k<<<32, 256, 0, stream>>>(rowsum, pos, out);
}

// Round 8
// 39.004 us; speedup vs baseline: 1.1918x; 1.1918x over previous
//
#include <hip/hip_runtime.h>
#include <hip/hip_bf16.h>
#include <math.h>

typedef __attribute__((ext_vector_type(4))) float f32x4;

#define N 8192
#define D 256
#define INV_T 10.0f
#define EPSN 1e-8f

__device__ __forceinline__ void async16(void* lds, const void* g) {
  __builtin_amdgcn_global_load_lds(
      (const __attribute__((address_space(1))) void*)g,
      (__attribute__((address_space(3))) void*)lds,
      16, 0, 0);
}

// Sum over each 16-lane group via DPP row_shr adds (VALU pipe, no DS traffic).
// Result valid in lane 15 of each group.
__device__ __forceinline__ float rowsum16(float v) {
  v += __uint_as_float(__builtin_amdgcn_update_dpp(
      0u, __float_as_uint(v), 0x118, 0xf, 0xf, true));  // row_shr:8
  v += __uint_as_float(__builtin_amdgcn_update_dpp(
      0u, __float_as_uint(v), 0x114, 0xf, 0xf, true));  // row_shr:4
  v += __uint_as_float(__builtin_amdgcn_update_dpp(
      0u, __float_as_uint(v), 0x112, 0xf, 0xf, true));  // row_shr:2
  v += __uint_as_float(__builtin_amdgcn_update_dpp(
      0u, __float_as_uint(v), 0x111, 0xf, 0xf, true));  // row_shr:1
  return v;
}

// One wave per row: fp32 norm, fp8-e4m3 normalized row. Also zeroes rowsum+out.
__global__ __launch_bounds__(256) void normalize_k(const float* __restrict__ feats,
                                                   unsigned char* __restrict__ fn,
                                                   float* __restrict__ rowsum,
                                                   float* __restrict__ out) {
  int row = blockIdx.x * 4 + (threadIdx.x >> 6);
  int lane = threadIdx.x & 63;
  if (threadIdx.x < 4) rowsum[blockIdx.x * 4 + threadIdx.x] = 0.0f;
  if (blockIdx.x == 0 && threadIdx.x == 0) out[0] = 0.0f;
  float4 v = ((const float4*)(feats + (size_t)row * D))[lane];
  float ss = v.x * v.x + v.y * v.y + v.z * v.z + v.w * v.w;
#pragma unroll
  for (int off = 32; off; off >>= 1) ss += __shfl_xor(ss, off, 64);
  float inv = 1.0f / fmaxf(sqrtf(ss), EPSN);
  int w = __builtin_amdgcn_cvt_pk_fp8_f32(v.x * inv, v.y * inv, 0, false);
  w = __builtin_amdgcn_cvt_pk_fp8_f32(v.z * inv, v.w * inv, w, true);
  ((int*)(fn + (size_t)row * D))[lane] = w;
}

// Fused symmetric GEMM (C = fn*fn^T/T, fp8 e4m3) + exp(C-10) row/col-sum +
// pos harvest. 128x128 tile, triangular blocks (bm<=bn), BK=64, 8 waves
// (2x4, 64x32 each), 16x16x32 fp8 MFMA (bf16-class rate, half operand bytes).
// LDS = 33KB/block -> 4 blocks/CU (full 32-wave occupancy). Chunk-swizzled
// LDS: 16B chunk (r,c) stored at 4r + (c ^ ((r>>1)&3)) -- keeps the
// global_load_lds source 16B-contiguous AND gives 2-way (free) banks on the
// b64 fragment reads. Counted-vmcnt pipeline, DPP row-reduce epilogue.
__global__ __launch_bounds__(512, 8) void gemm_lse(const unsigned char* __restrict__ fn,
                                                   float* __restrict__ rowsum,
                                                   float* __restrict__ pos) {
  __shared__ unsigned char As[2][8192];
  __shared__ unsigned char Bs[2][8192];
  __shared__ float lrow[128];
  __shared__ float lcol[128];
  int tid = threadIdx.x;
  int wave = tid >> 6, lane = tid & 63;
  int wm = wave >> 2, wn = wave & 3;
  int hi = lane >> 4, lo = lane & 15;

  // XCD-chunked triangular order: 2080 = 8 * 260, bijective.
  int b = blockIdx.x;
  int t = (b & 7) * 260 + (b >> 3);
  int bm = (int)((129.0 - sqrt((double)(16641 - 8 * t))) * 0.5);
  int S = bm * (129 - bm) / 2;
  if (t < S) { --bm; S = bm * (129 - bm) / 2; }
  else { int S1 = (bm + 1) * (128 - bm) / 2; if (t >= S1) { ++bm; S = S1; } }
  int bn = bm + (t - S);

  // Staging: 512 threads x 16B = one full 128x64B tile per array.
  // Dest chunk d=tid holds source chunk (r = d>>2, c = (d&3) ^ ((r>>1)&3)).
  int sr = tid >> 2;
  int sc = (tid & 3) ^ ((sr >> 1) & 3);
  const unsigned char* gsa = fn + (size_t)(bm * 128 + sr) * D + sc * 16;
  const unsigned char* gsb = fn + (size_t)(bn * 128 + sr) * D + sc * 16;
  auto stage = [&](int buf, int kt) {
    async16(&As[buf][tid * 16], gsa + kt * 64);
    async16(&Bs[buf][tid * 16], gsb + kt * 64);
  };

  // LDS byte offsets for the b64 fragment reads (buf-independent).
  // Element (R, k): chunk c0=k>>4 at 4R + (c0 ^ ((R>>1)&3)), byte k&15.
  int offA[4][2], offB[2][2];
#pragma unroll
  for (int m = 0; m < 4; ++m) {
    int R = wm * 64 + m * 16 + lo;
#pragma unroll
    for (int ks = 0; ks < 2; ++ks)
      offA[m][ks] = R * 64 + ((((ks << 1) | (hi >> 1)) ^ ((R >> 1) & 3)) << 4) +
                    ((hi & 1) << 3);
  }
#pragma unroll
  for (int n = 0; n < 2; ++n) {
    int R = wn * 32 + n * 16 + lo;
#pragma unroll
    for (int ks = 0; ks < 2; ++ks)
      offB[n][ks] = R * 64 + ((((ks << 1) | (hi >> 1)) ^ ((R >> 1) & 3)) << 4) +
                    ((hi & 1) << 3);
  }

  f32x4 acc[4][2];
#pragma unroll
  for (int m = 0; m < 4; ++m)
#pragma unroll
    for (int n = 0; n < 2; ++n) acc[m][n] = (f32x4){0.f, 0.f, 0.f, 0.f};

  auto compute = [&](int buf) {
#pragma unroll
    for (int ks = 0; ks < 2; ++ks) {
      long long a[4], bb[2];
#pragma unroll
      for (int m = 0; m < 4; ++m)
        a[m] = *(const long long*)&As[buf][offA[m][ks]];
#pragma unroll
      for (int n = 0; n < 2; ++n)
        bb[n] = *(const long long*)&Bs[buf][offB[n][ks]];
#pragma unroll
      for (int m = 0; m < 4; ++m)
#pragma unroll
        for (int n = 0; n < 2; ++n)
          acc[m][n] = __builtin_amdgcn_mfma_f32_16x16x32_fp8_fp8(
              a[m], bb[n], acc[m][n], 0, 0, 0);
    }
  };

  stage(0, 0);          // 2 loads/thread
  stage(1, 1);          // 2 more: 4 outstanding
  if (tid < 128) { lrow[tid] = 0.0f; lcol[tid] = 0.0f; }

#pragma unroll
  for (int kt = 0; kt < 4; ++kt) {
    if (kt < 3) asm volatile("s_waitcnt vmcnt(2)" ::: "memory");
    else        asm volatile("s_waitcnt vmcnt(0)" ::: "memory");
    __builtin_amdgcn_s_barrier();        // all waves' tile-kt loads landed
    __builtin_amdgcn_sched_barrier(0);   // pin ds_reads below the barrier
    compute(kt & 1);
    asm volatile("s_waitcnt lgkmcnt(0)" ::: "memory");  // own ds_reads done
    __builtin_amdgcn_sched_barrier(0);
    __builtin_amdgcn_s_barrier();        // WAR: everyone done reading buf
    if (kt < 2) stage(kt & 1, kt + 2);   // refill the buffer just consumed
  }

  // Epilogue. C frag layout: col = lane&15, row = (lane>>4)*4 + reg.
  bool isdiag = (bm == bn);
  float ca[2] = {0.f, 0.f};
  int rbase = wm * 64, cbase = wn * 32;
#pragma unroll
  for (int m = 0; m < 4; ++m) {
#pragma unroll
    for (int j = 0; j < 4; ++j) {
      int rloc = rbase + m * 16 + hi * 4 + j;
      float v = 0.f;
#pragma unroll
      for (int n = 0; n < 2; ++n) {
        float e = __expf(fmaf(acc[m][n][j], 10.0f, -10.0f));
        if (isdiag && rloc == cbase + n * 16 + lo) e = 0.f;
        v += e;
        ca[n] += e;
      }
      v = rowsum16(v);  // DPP: VALU pipe, no DS traffic
      if (lo == 15) atomicAdd(&lrow[rloc], v);
    }
  }
  if (!isdiag) {
#pragma unroll
    for (int n = 0; n < 2; ++n) {
      float c = ca[n];
      c += __shfl_xor(c, 16, 64);
      c += __shfl_xor(c, 32, 64);
      if (hi == 0) atomicAdd(&lcol[cbase + n * 16 + lo], c);
    }
  }
  // pos harvest: block (bm, bm+32) local diagonal = sim[i, i+4096].
  if (bn == bm + 32) {
#pragma unroll
    for (int m = 0; m < 4; ++m) {
      int rb = wm * 64 + m * 16;
#pragma unroll
      for (int n = 0; n < 2; ++n) {
        if (rb == wn * 32 + n * 16 && (lo >> 2) == hi) {
          int j = lo & 3;
          f32x4 a = acc[m][n];
          float pv = (j == 0) ? a[0] : (j == 1) ? a[1] : (j == 2) ? a[2] : a[3];
          pv *= INV_T;
          int gr = bm * 128 + rb + lo;
          pos[gr] = pv;
          pos[gr + N / 2] = pv;
        }
      }
    }
  }
  __syncthreads();
  if (tid < 128) {
    atomicAdd(&rowsum[bm * 128 + tid], lrow[tid]);
    if (!isdiag) atomicAdd(&rowsum[bn * 128 + tid], lcol[tid]);
  }
}

// 32 blocks x 256 threads: one row each, partial-reduce, atomic accumulate.
__global__ __launch_bounds__(256) void final_k(const float* __restrict__ rowsum,
                                               const float* __restrict__ pos,
                                               float* __restrict__ out) {
  int tid = threadIdx.x;
  int i = blockIdx.x * 256 + tid;
  float s = 10.0f + logf(rowsum[i]) - pos[i];
#pragma unroll
  for (int off = 32; off; off >>= 1) s += __shfl_xor(s, off, 64);
  __shared__ float red[4];
  if ((tid & 63) == 0) red[tid >> 6] = s;
  __syncthreads();
  if (tid == 0)
    atomicAdd(out, (red[0] + red[1] + red[2] + red[3]) * (1.0f / N));
}

extern "C" void kernel_launch(void* const* d_in, const int* in_sizes, int n_in,
                              void* d_out, int out_size, void* d_ws, size_t ws_size,
                              hipStream_t stream) {
  const float* feats = (const float*)d_in[0];
  float* out = (float*)d_out;
  char* ws = (char*)d_ws;
  unsigned char* fn = (unsigned char*)ws;                      // 2 MB fp8 normalized feats
  float* pos = (float*)(ws + 2 * 1024 * 1024);                 // 32 KB
  float* rowsum = (float*)(ws + 2 * 1024 * 1024 + 32 * 1024);  // 32 KB

  normalize_k<<<N / 4, 256, 0, stream>>>(feats, fn, rowsum, out);
  gemm_lse<<<(64 * 65) / 2, 512, 0, stream>>>(fn, rowsum, pos);
  final_k<<<32, 256, 0, stream>>>(rowsum, pos, out);
}